// Round 1
// baseline (138.869 us; speedup 1.0000x reference)
//
#include <hip/hip_runtime.h>
#include <math.h>

typedef __attribute__((ext_vector_type(8))) short short8;
typedef __attribute__((ext_vector_type(4))) float f32x4;
typedef unsigned short u16;

#define DEV static __device__ __forceinline__

DEV u16 f2bf(float f) {
  union { float f; unsigned u; } v; v.f = f;
  unsigned r = v.u + 0x7FFFu + ((v.u >> 16) & 1u);
  return (u16)(r >> 16);
}
DEV float bf2f(u16 u) {
  union { unsigned u; float f; } v; v.u = ((unsigned)u) << 16;
  return v.f;
}

// ---------------- K0: convert weights to bf16 ----------------
// W: 1024x1024 (out_proj_w, row-major [e][k]), Wf: 1024x64 (ffn_lin_w [e][k])
__global__ __launch_bounds__(256) void k_conv(const float* __restrict__ W,
                                              const float* __restrict__ Wf,
                                              u16* __restrict__ Wb,
                                              u16* __restrict__ Wfb) {
  int i = (blockIdx.x * 256 + threadIdx.x) * 4;
  const int NW = 1024 * 1024;
  if (i < NW) {
    float4 v = *(const float4*)(W + i);
    ushort4 o = {f2bf(v.x), f2bf(v.y), f2bf(v.z), f2bf(v.w)};
    *(ushort4*)(Wb + i) = o;
  } else {
    int j = i - NW;  // < 65536
    float4 v = *(const float4*)(Wf + j);
    ushort4 o = {f2bf(v.x), f2bf(v.y), f2bf(v.z), f2bf(v.w)};
    *(ushort4*)(Wfb + j) = o;
  }
}

// ---------------- K1: z = cos(x + a0[d]) * cos(a1[d]), bf16 ----------------
__global__ __launch_bounds__(256) void k_zenc(const float* __restrict__ x,
                                              const float* __restrict__ qp, // [64][3]
                                              u16* __restrict__ z) {
  __shared__ float a0[64], c1[64];
  int t = threadIdx.x;
  if (t < 64) { a0[t] = qp[t * 3]; c1[t] = cosf(qp[t * 3 + 1]); }
  __syncthreads();
  size_t i = ((size_t)blockIdx.x * 256 + t) * 4;
  float4 xv = *(const float4*)(x + i);
  int d = (int)(i & 63);  // 4 consecutive d's within the 64-group
  ushort4 o;
  o.x = f2bf(cosf(xv.x + a0[d + 0]) * c1[d + 0]);
  o.y = f2bf(cosf(xv.y + a0[d + 1]) * c1[d + 1]);
  o.z = f2bf(cosf(xv.z + a0[d + 2]) * c1[d + 2]);
  o.w = f2bf(cosf(xv.w + a0[d + 3]) * c1[d + 3]);
  *(ushort4*)(z + i) = o;
}

// ---------------- K2: Y = Z @ W^T + x + bias   (fp32 out into d_out) -------
// M=16384, N=1024, K=1024. 128x128 tile, BK=32, 4 waves, m97 structure.
__global__ __launch_bounds__(256) void k_gemm(const u16* __restrict__ Z,
                                              const u16* __restrict__ Wb,
                                              const float* __restrict__ x,
                                              const float* __restrict__ bias,
                                              float* __restrict__ Y) {
  constexpr int K = 1024, N = 1024;
  __shared__ __attribute__((aligned(16))) u16 As[2][128 * 32];
  __shared__ __attribute__((aligned(16))) u16 Bs[2][128 * 32];
  int bid = blockIdx.x;
  // XCD swizzle: nwg=1024, 8 XCDs -> each XCD gets 16 m-tiles x full N (W fits its L2)
  int wg = (bid & 7) * 128 + (bid >> 3);
  int mt = wg >> 3, nt = wg & 7;
  int m0 = mt * 128, n0 = nt * 128;
  int t = threadIdx.x, lane = t & 63, wv = t >> 6;
  int wr = wv >> 1, wc = wv & 1;

  int srow = t >> 2;        // 0..63
  int scol = (t & 3) * 8;   // 0,8,16,24
  const u16* gA = Z + (size_t)(m0 + srow) * K + scol;
  const u16* gB = Wb + (size_t)(n0 + srow) * K + scol;
  int lbase = wv * 512;     // wave-uniform LDS elem base (lane*8 added by HW)

  f32x4 acc[4][4];
#pragma unroll
  for (int i = 0; i < 4; ++i)
#pragma unroll
    for (int j = 0; j < 4; ++j) acc[i][j] = (f32x4){0.f, 0.f, 0.f, 0.f};

  auto stage = [&](int buf, int kt) {
    const u16* ga = gA + kt * 32;
    const u16* gb = gB + kt * 32;
#pragma unroll
    for (int j = 0; j < 2; ++j) {
      __builtin_amdgcn_global_load_lds(
          (const __attribute__((address_space(1))) unsigned int*)(ga + (size_t)j * 64 * K),
          (__attribute__((address_space(3))) unsigned int*)&As[buf][j * 2048 + lbase],
          16, 0, 0);
      __builtin_amdgcn_global_load_lds(
          (const __attribute__((address_space(1))) unsigned int*)(gb + (size_t)j * 64 * K),
          (__attribute__((address_space(3))) unsigned int*)&Bs[buf][j * 2048 + lbase],
          16, 0, 0);
    }
  };

  stage(0, 0);
  int kof = (lane >> 4) * 8;
  int arow = wr * 64 + (lane & 15);
  int brow = wc * 64 + (lane & 15);
  int cur = 0;
  for (int kt = 0; kt < K / 32; ++kt) {
    __syncthreads();                       // drains vmcnt -> buf[cur] ready
    if (kt + 1 < K / 32) stage(cur ^ 1, kt + 1);
    short8 av[4], bv[4];
#pragma unroll
    for (int mi = 0; mi < 4; ++mi)
      av[mi] = *(const short8*)&As[cur][(arow + mi * 16) * 32 + kof];
#pragma unroll
    for (int ni = 0; ni < 4; ++ni)
      bv[ni] = *(const short8*)&Bs[cur][(brow + ni * 16) * 32 + kof];
#pragma unroll
    for (int mi = 0; mi < 4; ++mi)
#pragma unroll
      for (int ni = 0; ni < 4; ++ni)
        acc[mi][ni] = __builtin_amdgcn_mfma_f32_16x16x32_bf16(av[mi], bv[ni], acc[mi][ni], 0, 0, 0);
    cur ^= 1;
  }
  // epilogue: C layout col=lane&15, row=(lane>>4)*4+r  (m89-verified)
  int r0 = m0 + wr * 64 + (lane >> 4) * 4;
  int c0 = n0 + wc * 64 + (lane & 15);
#pragma unroll
  for (int mi = 0; mi < 4; ++mi) {
#pragma unroll
    for (int ni = 0; ni < 4; ++ni) {
      int col = c0 + ni * 16;
      float bcol = bias[col];
#pragma unroll
      for (int r = 0; r < 4; ++r) {
        size_t idx = (size_t)(r0 + mi * 16 + r) * N + col;
        Y[idx] = acc[mi][ni][r] + x[idx] + bcol;
      }
    }
  }
}

// ---------------- K3: x1 = LN1(Y), q = cos(x1[:,:64]+f0)*cos(f1) ----------
__global__ __launch_bounds__(256) void k_ln1(const float* __restrict__ Y,
                                             const float* __restrict__ w1,
                                             const float* __restrict__ b1,
                                             const float* __restrict__ fqp, // [64][3]
                                             u16* __restrict__ X1,
                                             u16* __restrict__ Q) {
  int t = threadIdx.x, lane = t & 63, wv = t >> 6;
  int row = blockIdx.x * 4 + wv;
  const float* yr = Y + (size_t)row * 1024;
  float4 v[4];
  float s = 0.f, s2 = 0.f;
#pragma unroll
  for (int j = 0; j < 4; ++j) {
    v[j] = *(const float4*)(yr + j * 256 + lane * 4);
    s += v[j].x + v[j].y + v[j].z + v[j].w;
    s2 += v[j].x * v[j].x + v[j].y * v[j].y + v[j].z * v[j].z + v[j].w * v[j].w;
  }
#pragma unroll
  for (int m = 1; m < 64; m <<= 1) { s += __shfl_xor(s, m, 64); s2 += __shfl_xor(s2, m, 64); }
  float mu = s * (1.f / 1024.f);
  float var = s2 * (1.f / 1024.f) - mu * mu;
  float rs = rsqrtf(var + 1e-5f);
  float q0[4];
#pragma unroll
  for (int j = 0; j < 4; ++j) {
    int col = j * 256 + lane * 4;
    float4 wv4 = *(const float4*)(w1 + col);
    float4 bv4 = *(const float4*)(b1 + col);
    float o0 = (v[j].x - mu) * rs * wv4.x + bv4.x;
    float o1 = (v[j].y - mu) * rs * wv4.y + bv4.y;
    float o2 = (v[j].z - mu) * rs * wv4.z + bv4.z;
    float o3 = (v[j].w - mu) * rs * wv4.w + bv4.w;
    ushort4 o = {f2bf(o0), f2bf(o1), f2bf(o2), f2bf(o3)};
    *(ushort4*)(X1 + (size_t)row * 1024 + col) = o;
    if (j == 0) { q0[0] = o0; q0[1] = o1; q0[2] = o2; q0[3] = o3; }
  }
  if (lane < 16) {
    ushort4 qo;
    u16* qs = (u16*)&qo;
#pragma unroll
    for (int c = 0; c < 4; ++c) {
      int col = lane * 4 + c;
      qs[c] = f2bf(cosf(q0[c] + fqp[col * 3]) * cosf(fqp[col * 3 + 1]));
    }
    *(ushort4*)(Q + (size_t)row * 64 + lane * 4) = qo;
  }
}

// ---------------- K4: ffn = Q @ Wf^T; out = LN2(x1 + ffn + fb) ------------
// Block: 16 rows, N=1024 across 4 waves (256 cols each), K=64 via 2 MFMAs.
__global__ __launch_bounds__(256) void k_ffn(const u16* __restrict__ X1,
                                             const u16* __restrict__ Q,
                                             const u16* __restrict__ Wfb,
                                             const float* __restrict__ fb,
                                             const float* __restrict__ w2,
                                             const float* __restrict__ b2,
                                             float* __restrict__ out) {
  __shared__ float t2[16][1024];  // 64 KB
  int t = threadIdx.x, lane = t & 63, wv = t >> 6;
  int m0 = blockIdx.x * 16;
  int kof = (lane >> 4) * 8;
  const short8 a0v = *(const short8*)&Q[(size_t)(m0 + (lane & 15)) * 64 + kof];
  const short8 a1v = *(const short8*)&Q[(size_t)(m0 + (lane & 15)) * 64 + 32 + kof];
  int nbase = wv * 256;
#pragma unroll
  for (int ni = 0; ni < 16; ++ni) {
    int n = nbase + ni * 16 + (lane & 15);
    short8 b0 = *(const short8*)&Wfb[(size_t)n * 64 + kof];
    short8 b1 = *(const short8*)&Wfb[(size_t)n * 64 + 32 + kof];
    f32x4 acc = (f32x4){0.f, 0.f, 0.f, 0.f};
    acc = __builtin_amdgcn_mfma_f32_16x16x32_bf16(a0v, b0, acc, 0, 0, 0);
    acc = __builtin_amdgcn_mfma_f32_16x16x32_bf16(a1v, b1, acc, 0, 0, 0);
#pragma unroll
    for (int r = 0; r < 4; ++r) t2[(lane >> 4) * 4 + r][n] = acc[r];
  }
  __syncthreads();
  for (int rr = 0; rr < 4; ++rr) {
    int row = wv * 4 + rr;
    size_t grow = (size_t)(m0 + row) * 1024;
    float vv[16];
    float s = 0.f, s2 = 0.f;
#pragma unroll
    for (int j = 0; j < 16; ++j) {
      int col = j * 64 + lane;
      float val = bf2f(X1[grow + col]) + t2[row][col] + fb[col];
      vv[j] = val; s += val; s2 += val * val;
    }
#pragma unroll
    for (int m = 1; m < 64; m <<= 1) { s += __shfl_xor(s, m, 64); s2 += __shfl_xor(s2, m, 64); }
    float mu = s * (1.f / 1024.f);
    float var = s2 * (1.f / 1024.f) - mu * mu;
    float rs = rsqrtf(var + 1e-5f);
#pragma unroll
    for (int j = 0; j < 16; ++j) {
      int col = j * 64 + lane;
      out[grow + col] = (vv[j] - mu) * rs * w2[col] + b2[col];
    }
  }
}

extern "C" void kernel_launch(void* const* d_in, const int* in_sizes, int n_in,
                              void* d_out, int out_size, void* d_ws, size_t ws_size,
                              hipStream_t stream) {
  const float* x   = (const float*)d_in[0];
  const float* aqp = (const float*)d_in[1];
  const float* opw = (const float*)d_in[2];
  const float* opb = (const float*)d_in[3];
  const float* fqp = (const float*)d_in[4];
  const float* flw = (const float*)d_in[5];
  const float* flb = (const float*)d_in[6];
  const float* n1w = (const float*)d_in[7];
  const float* n1b = (const float*)d_in[8];
  const float* n2w = (const float*)d_in[9];
  const float* n2b = (const float*)d_in[10];
  float* Y = (float*)d_out;  // used as fp32 scratch for pre-LN1, then final out

  char* ws = (char*)d_ws;
  u16* zbuf = (u16*)(ws + 0);          // 16384*1024 bf16 (z, later reused as x1)
  u16* Wb   = (u16*)(ws + 33554432);   // 1024*1024 bf16
  u16* Wfb  = (u16*)(ws + 35651584);   // 1024*64 bf16
  u16* Qb   = (u16*)(ws + 35782656);   // 16384*64 bf16

  k_conv<<<1088, 256, 0, stream>>>(opw, flw, Wb, Wfb);
  k_zenc<<<16384, 256, 0, stream>>>(x, aqp, zbuf);
  k_gemm<<<1024, 256, 0, stream>>>(zbuf, Wb, x, opb, Y);
  k_ln1<<<4096, 256, 0, stream>>>(Y, n1w, n1b, fqp, zbuf /*X1 overwrites z*/, Qb);
  k_ffn<<<1024, 256, 0, stream>>>(zbuf, Qb, Wfb, flb, n2w, n2b, Y);
}